// Round 13
// baseline (293.236 us; speedup 1.0000x reference)
//
#include <hip/hip_runtime.h>

#define HH 256       // hidden size
#define NB 64        // batch (segments)
#define ROWS 128     // rows per block tile
#define NTOT 262144  // NK == NC
#define THREADS 512  // 8 waves = 4 j-quarters x 2 r-halves

typedef _Float16 half8 __attribute__((ext_vector_type(8)));
typedef _Float16 half4 __attribute__((ext_vector_type(4)));
typedef float f32x4 __attribute__((ext_vector_type(4)));

// act LDS tile: [row][k] fp16, 128 rows x 256 k = 64KB, row stride 512B.
__device__ __forceinline__ uint32_t swz(uint32_t r, uint32_t k) {
  return (((r << 9) + (k << 1)) ^ ((r & 7) << 4)) ^ ((r & 8) << 3);
}

// ---------------------------------------------------------------------------
// Heavy layer via MFMA, swapped operands: D[j][r] = sum_k WT[j][k]*act[r][k]
// *** W LIVES IN REGISTERS for the whole layer ***: 32 x half8 per lane
// (wave slice 64j x 256k = 512B/lane), loaded once per layer as 32 coalesced
// 16B loads from the pre-swizzled WF layout. The ks loop is then pure
// {4 ds_read_b128 -> 16 MFMA}: no vmcnt, no DMA, no A-LDS traffic.
// 8 waves: jq = wid>>1 (64j), rh = wid&1 (64r). Per wave: acc[4][4],
// 128 MFMAs. Block reads W once/layer; rh-pairs share W via L1.
// MODE: 0 relu; 1 plain (trunk c); 2 multiply seg_mean[seg_g[r]] (branch)
// ---------------------------------------------------------------------------
template<int MODE>
__device__ __forceinline__ void heavy_layer(char* act, const char* __restrict__ wf,
                                            const float* __restrict__ bias,
                                            const float* __restrict__ seg_mean,
                                            const int* __restrict__ seg_g, int tid)
{
  const int wid  = tid >> 6;
  const int lane = tid & 63;
  const int lr   = lane & 15;
  const int lg   = lane >> 4;
  const int jq   = wid >> 1;
  const int r0   = (wid & 1) << 6;
  const int j0   = jq << 6;

  // --- W into registers: 32 x 16B coalesced loads, all in flight at once ---
  const char* wfb = wf + (size_t)jq * 32768 + lane * 16;
  half8 w[4][8];  // [jf][ks] = 128 VGPRs
#pragma unroll
  for (int ks = 0; ks < 8; ++ks)
#pragma unroll
    for (int jf = 0; jf < 4; ++jf)
      w[jf][ks] = *(const half8*)(wfb + (jf * 8 + ks) * 1024);

  f32x4 acc[4][4];  // [jf][rf]
#pragma unroll
  for (int jf = 0; jf < 4; ++jf)
#pragma unroll
    for (int rf = 0; rf < 4; ++rf)
      acc[jf][rf] = (f32x4){0.f, 0.f, 0.f, 0.f};

#pragma unroll
  for (int ks = 0; ks < 8; ++ks) {
    half8 b[4];
#pragma unroll
    for (int rf = 0; rf < 4; ++rf)
      b[rf] = *(const half8*)(act + swz(r0 + rf * 16 + lr, ks * 32 + lg * 8));
#pragma unroll
    for (int jf = 0; jf < 4; ++jf)
#pragma unroll
      for (int rf = 0; rf < 4; ++rf)
        acc[jf][rf] = __builtin_amdgcn_mfma_f32_16x16x32_f16(w[jf][ks], b[rf], acc[jf][rf], 0, 0, 0);
    __builtin_amdgcn_sched_barrier(0);  // keep next step's b-reads from hoisting
  }

  int sseg[4];
  if (MODE == 2) {
#pragma unroll
    for (int rf = 0; rf < 4; ++rf) sseg[rf] = seg_g[r0 + rf * 16 + lr];
  }

  __syncthreads();  // all waves done READING act before overwrite

#pragma unroll
  for (int jf = 0; jf < 4; ++jf) {
    f32x4 bj = *(const f32x4*)(bias + j0 + jf * 16 + lg * 4);
#pragma unroll
    for (int rf = 0; rf < 4; ++rf) {
      f32x4 v = acc[jf][rf] + bj;
      if (MODE == 2) {
        f32x4 sm = *(const f32x4*)(seg_mean + sseg[rf] * HH + j0 + jf * 16 + lg * 4);
        v *= sm;
      }
      half4 h;
#pragma unroll
      for (int u = 0; u < 4; ++u) {
        float x = v[u];
        if (MODE == 0) x = fmaxf(x, 0.f);
        h[u] = (_Float16)x;
      }
      *(half4*)(act + swz(r0 + rf * 16 + lr, j0 + jf * 16 + lg * 4)) = h;
    }
  }
  __syncthreads();  // act tile complete for next layer
}

// layer 1 via MFMA: F=3 -> H (relu), K padded 3 -> 32 with zeros.
__device__ __forceinline__ void layer1_mfma(char* act, const float* __restrict__ x,
                                            int r0g, const float* __restrict__ W0,
                                            const float* __restrict__ b0, int tid)
{
  const int wid  = tid >> 6;
  const int lane = tid & 63;
  const int lr   = lane & 15;
  const int lg   = lane >> 4;
  const int r0   = (wid & 1) << 6;
  const int j0   = (wid >> 1) << 6;

  half8 a[4];
#pragma unroll
  for (int jf = 0; jf < 4; ++jf) {
    half8 v = {0, 0, 0, 0, 0, 0, 0, 0};
    if (lg == 0) {
      int j = j0 + jf * 16 + lr;
      v[0] = (_Float16)W0[j];
      v[1] = (_Float16)W0[HH + j];
      v[2] = (_Float16)W0[2 * HH + j];
    }
    a[jf] = v;
  }

  f32x4 acc[4][4];
#pragma unroll
  for (int jf = 0; jf < 4; ++jf)
#pragma unroll
    for (int rf = 0; rf < 4; ++rf)
      acc[jf][rf] = (f32x4){0.f, 0.f, 0.f, 0.f};

#pragma unroll
  for (int rf = 0; rf < 4; ++rf) {
    half8 b = {0, 0, 0, 0, 0, 0, 0, 0};
    if (lg == 0) {
      const float* xp = x + (size_t)(r0g + r0 + rf * 16 + lr) * 3;
      b[0] = (_Float16)xp[0];
      b[1] = (_Float16)xp[1];
      b[2] = (_Float16)xp[2];
    }
#pragma unroll
    for (int jf = 0; jf < 4; ++jf)
      acc[jf][rf] = __builtin_amdgcn_mfma_f32_16x16x32_f16(a[jf], b, acc[jf][rf], 0, 0, 0);
  }

#pragma unroll
  for (int jf = 0; jf < 4; ++jf) {
    f32x4 bj = *(const f32x4*)(b0 + j0 + jf * 16 + lg * 4);
#pragma unroll
    for (int rf = 0; rf < 4; ++rf) {
      f32x4 v = acc[jf][rf] + bj;
      half4 h;
#pragma unroll
      for (int u = 0; u < 4; ++u)
        h[u] = (_Float16)fmaxf(v[u], 0.f);
      *(half4*)(act + swz(r0 + rf * 16 + lr, j0 + jf * 16 + lg * 4)) = h;
    }
  }
  __syncthreads();
}

// ---------------------------------------------------------------------------
__global__ __launch_bounds__(THREADS, 2)
void trunk_kernel(const float* __restrict__ nodes, const int* __restrict__ coord_seg,
                  const float* __restrict__ tw0, const float* __restrict__ tb0,
                  const char* __restrict__ wf1, const float* __restrict__ tb1,
                  const char* __restrict__ wf2, const float* __restrict__ tb2,
                  float* __restrict__ seg_sum)
{
  __shared__ __align__(16) char act[ROWS * HH * 2];  // 64KB
  const int tid = threadIdx.x;
  const int r0g = blockIdx.x * ROWS;

  layer1_mfma(act, nodes, r0g, tw0, tb0, tid);
  heavy_layer<0>(act, wf1, tb1, nullptr, nullptr, tid);
  heavy_layer<1>(act, wf2, tb2, nullptr, nullptr, tid);  // c

  // per-segment sums of c; 512 threads: j = tid&255, half = tid>>8 (64 rows).
  {
    const int j  = tid & 255;
    const int rb = (tid >> 8) * 64;
    const int s_lo = coord_seg[r0g + rb];
    const int s_hi = coord_seg[r0g + rb + 63];
    if (s_lo == s_hi) {
      float p = 0.f;
#pragma unroll 8
      for (int rr = 0; rr < 64; ++rr)
        p += (float)*(const _Float16*)(act + swz(rb + rr, j));
      atomicAdd(&seg_sum[s_lo * HH + j], p);
    } else {
      for (int s = s_lo; s <= s_hi; ++s) {
        float p = 0.f;
        for (int rr = 0; rr < 64; ++rr)
          if (coord_seg[r0g + rb + rr] == s)
            p += (float)*(const _Float16*)(act + swz(rb + rr, j));
        atomicAdd(&seg_sum[s * HH + j], p);
      }
    }
  }
}

__global__ __launch_bounds__(THREADS, 2)
void branch_kernel(const float* __restrict__ known_nodes, const int* __restrict__ known_seg,
                   const float* __restrict__ bw0, const float* __restrict__ bb0,
                   const char* __restrict__ wf1, const float* __restrict__ bb1,
                   const char* __restrict__ wf2, const float* __restrict__ bb2,
                   const float* __restrict__ seg_mean,
                   const char* __restrict__ wfo, const float* __restrict__ ob0,
                   const float* __restrict__ ow1, const float* __restrict__ ob1,
                   float* __restrict__ out)
{
  __shared__ __align__(16) char act[ROWS * HH * 2];  // 64KB
  __shared__ float ps[4 * ROWS * 3];                 // tail partials, 6KB
  const int tid = threadIdx.x;
  const int r0g = blockIdx.x * ROWS;

  layer1_mfma(act, known_nodes, r0g, bw0, bb0, tid);
  heavy_layer<0>(act, wf1, bb1, nullptr, nullptr, tid);
  heavy_layer<2>(act, wf2, bb2, seg_mean, known_seg + r0g, tid);  // f*seg_mean
  heavy_layer<0>(act, wfo, ob0, nullptr, nullptr, tid);           // relu(.@ow0+ob0)

  // out = h @ ow1 + ob1 (256 -> 3): 512 threads, 4 k-quarters in parallel
  {
    const int r = tid & 127;
    const int q = tid >> 7;
    float o0 = 0.f, o1 = 0.f, o2 = 0.f;
    for (int kk = 0; kk < 64; kk += 8) {
      int k0 = q * 64 + kk;
      half8 h = *(const half8*)(act + swz(r, k0));
#pragma unroll
      for (int u = 0; u < 8; ++u) {
        float a = (float)h[u];
        o0 = fmaf(a, ow1[(k0 + u) * 3 + 0], o0);
        o1 = fmaf(a, ow1[(k0 + u) * 3 + 1], o1);
        o2 = fmaf(a, ow1[(k0 + u) * 3 + 2], o2);
      }
    }
    float* p = ps + q * ROWS * 3;
    p[r * 3 + 0] = o0; p[r * 3 + 1] = o1; p[r * 3 + 2] = o2;
  }
  __syncthreads();
  if (tid < ROWS) {
    const int r = tid;
    float* dst = out + (size_t)(r0g + r) * 3;
#pragma unroll
    for (int c = 0; c < 3; ++c) {
      float o = ob1[c];
#pragma unroll
      for (int q = 0; q < 4; ++q) o += ps[q * ROWS * 3 + r * 3 + c];
      dst[c] = o;
    }
  }
}

// W[256][256] fp32 (row=k, col=j) -> WF reg-fragment layout fp16:
// off = (j>>6)*32768 + (((j>>4)&3)*8 + (k>>5))*1024
//     + ((((k>>3)&3)<<4) | (j&15))*16 + (k&7)*2
struct WPtrs { const float* w[5]; char* wf[5]; };
__global__ void transpose_kernel(WPtrs p)
{
  const int m = blockIdx.x >> 8;   // matrix
  const int k = blockIdx.x & 255;  // input dim
  const int j = threadIdx.x;       // output dim
  size_t off = (size_t)(j >> 6) * 32768
             + (size_t)(((j >> 4) & 3) * 8 + (k >> 5)) * 1024
             + (size_t)((((k >> 3) & 3) << 4) | (j & 15)) * 16
             + (size_t)(k & 7) * 2;
  *(_Float16*)(p.wf[m] + off) = (_Float16)p.w[m][k * HH + j];
}

__global__ void zero_kernel(float* __restrict__ p, int n)
{
  int i = blockIdx.x * blockDim.x + threadIdx.x;
  if (i < n) p[i] = 0.f;
}

__global__ void mean_kernel(const float* __restrict__ seg_sum,
                            const int* __restrict__ coord_seg,
                            float* __restrict__ seg_mean)
{
  const int b = blockIdx.x;
  int lo = 0, n = NTOT;
  while (n > 0) { int h = n >> 1; int mid = lo + h;
    if (coord_seg[mid] < b) { lo = mid + 1; n -= h + 1; } else n = h; }
  int hi = lo; n = NTOT - lo;
  while (n > 0) { int h = n >> 1; int mid = hi + h;
    if (coord_seg[mid] < b + 1) { hi = mid + 1; n -= h + 1; } else n = h; }
  float inv = 1.0f / fmaxf((float)(hi - lo), 1.0f);
  seg_mean[b * HH + threadIdx.x] = seg_sum[b * HH + threadIdx.x] * inv;
}

// ---------------------------------------------------------------------------
extern "C" void kernel_launch(void* const* d_in, const int* in_sizes, int n_in,
                              void* d_out, int out_size, void* d_ws, size_t ws_size,
                              hipStream_t stream)
{
  const float* known_nodes = (const float*)d_in[0];
  const float* nodes       = (const float*)d_in[1];
  const int*   known_seg   = (const int*)d_in[2];
  const int*   coord_seg   = (const int*)d_in[3];
  const float* bw0 = (const float*)d_in[4];
  const float* bb0 = (const float*)d_in[5];
  const float* bw1 = (const float*)d_in[6];
  const float* bb1 = (const float*)d_in[7];
  const float* bw2 = (const float*)d_in[8];
  const float* bb2 = (const float*)d_in[9];
  const float* tw0 = (const float*)d_in[10];
  const float* tb0 = (const float*)d_in[11];
  const float* tw1 = (const float*)d_in[12];
  const float* tb1 = (const float*)d_in[13];
  const float* tw2 = (const float*)d_in[14];
  const float* tb2 = (const float*)d_in[15];
  const float* ow0 = (const float*)d_in[16];
  const float* ob0 = (const float*)d_in[17];
  const float* ow1 = (const float*)d_in[18];
  const float* ob1 = (const float*)d_in[19];

  float* out      = (float*)d_out;
  float* seg_sum  = (float*)d_ws;                        // [64][256] f32
  float* seg_mean = seg_sum + NB * HH;                   // [64][256] f32
  char* wfb       = (char*)d_ws + (size_t)2 * NB * HH * 4;
  char* wf_tw1 = wfb + 0 * (size_t)HH * HH * 2;
  char* wf_tw2 = wfb + 1 * (size_t)HH * HH * 2;
  char* wf_bw1 = wfb + 2 * (size_t)HH * HH * 2;
  char* wf_bw2 = wfb + 3 * (size_t)HH * HH * 2;
  char* wf_ow0 = wfb + 4 * (size_t)HH * HH * 2;

  WPtrs wp;
  wp.w[0] = tw1; wp.wf[0] = wf_tw1;
  wp.w[1] = tw2; wp.wf[1] = wf_tw2;
  wp.w[2] = bw1; wp.wf[2] = wf_bw1;
  wp.w[3] = bw2; wp.wf[3] = wf_bw2;
  wp.w[4] = ow0; wp.wf[4] = wf_ow0;

  transpose_kernel<<<5 * 256, 256, 0, stream>>>(wp);
  zero_kernel<<<(NB * HH + 255) / 256, 256, 0, stream>>>(seg_sum, NB * HH);
  trunk_kernel<<<NTOT / ROWS, THREADS, 0, stream>>>(nodes, coord_seg,
                                                    tw0, tb0, wf_tw1, tb1, wf_tw2, tb2,
                                                    seg_sum);
  mean_kernel<<<NB, 256, 0, stream>>>(seg_sum, coord_seg, seg_mean);
  branch_kernel<<<NTOT / ROWS, THREADS, 0, stream>>>(known_nodes, known_seg,
                                                     bw0, bb0, wf_bw1, bb1, wf_bw2, bb2,
                                                     seg_mean,
                                                     wf_ow0, ob0, ow1, ob1,
                                                     out);
}